// Round 3
// baseline (446.650 us; speedup 1.0000x reference)
//
#include <hip/hip_runtime.h>
#include <hip/hip_bf16.h>
#include <stdint.h>

#define NCAT 32
#define DIN  1536
#define DMID 1024
#define NB   128
#define TT   32

#define BM 128
#define BN 64
#define BK 32
#define LDA 40   // ushort stride for A tile rows (padded, 16B-aligned, spreads banks)
#define MAXG 56  // max groups: sum ceil(n_c/4) <= 56
#define NTILE 16 // 1024 / BN

typedef __attribute__((ext_vector_type(8))) short short8;
typedef __attribute__((ext_vector_type(4))) float f32x4;

static __device__ __forceinline__ unsigned int pk2bf(float lo, float hi) {
  unsigned short a = __builtin_bit_cast(unsigned short, __float2bfloat16(lo));
  unsigned short b = __builtin_bit_cast(unsigned short, __float2bfloat16(hi));
  return ((unsigned int)b << 16) | (unsigned int)a;
}

// ws int layout: [0..127] batch_list sorted by category; [128] num_groups;
// [132 + 4g ..] = {cat, start, cnt, pad}.
// byte 8192:            x in bf16 (128*32*1536*2 = 12582912 B)
// byte 8192+12582912:   hidden bf16 (4096*1024*2 = 8388608 B)
__global__ void build_groups(const int* __restrict__ cat_ids, int* __restrict__ wsi) {
  __shared__ int cats[NB];
  __shared__ int cnt[NCAT];
  __shared__ int off[NCAT];
  int t = threadIdx.x; // blockDim = 128
  cats[t] = cat_ids[t];
  __syncthreads();
  if (t < NCAT) {
    int n = 0;
    for (int b = 0; b < NB; b++) n += (cats[b] == t);
    cnt[t] = n;
  }
  __syncthreads();
  if (t == 0) {
    int acc = 0;
    for (int c = 0; c < NCAT; c++) { off[c] = acc; acc += cnt[c]; }
  }
  __syncthreads();
  if (t < NCAT) {
    int o = off[t];
    for (int b = 0; b < NB; b++)
      if (cats[b] == t) wsi[o++] = b;
  }
  if (t == 0) {
    int g = 0;
    for (int c = 0; c < NCAT; c++) {
      int n = cnt[c], o = off[c];
      for (int j = 0; j < n; j += 4) {
        wsi[132 + g * 4 + 0] = c;
        wsi[132 + g * 4 + 1] = o + j;
        wsi[132 + g * 4 + 2] = (n - j) < 4 ? (n - j) : 4;
        g++;
      }
    }
    wsi[128] = g;
  }
}

// x fp32 -> bf16, 8 floats per thread; n = 6291456 = 3072 blocks * 256 * 8
__global__ void cvt_x_bf16(const float* __restrict__ in, unsigned short* __restrict__ out) {
  int i = blockIdx.x * 256 + threadIdx.x;
  const float4* p = (const float4*)in + (size_t)i * 2;
  float4 a = p[0], b = p[1];
  ((uint4*)out)[i] = make_uint4(pk2bf(a.x, a.y), pk2bf(a.z, a.w),
                                pk2bf(b.x, b.y), pk2bf(b.z, b.w));
}

// A is bf16 for both layers (layer1: pre-converted x, layer2: hidden).
// LAYER 1: relu + bf16 store to hidden.  LAYER 2: + fp32 store to out.
template <int LAYER>
__global__ __launch_bounds__(256)
void mlp_gemm(const unsigned short* __restrict__ A, const float* __restrict__ W,
              const float* __restrict__ bias, const int* __restrict__ wsi,
              void* __restrict__ Out, int K) {
  // XCD-locality swizzle: all 16 n-tiles of a group share id%8 (same XCD
  // under round-robin dispatch) -> group's A tile stays in that XCD's L2.
  const int id = blockIdx.x;
  const int g  = (id & 7) + 8 * (id >> 7);
  const int t  = (id >> 3) & 15;
  if (g >= wsi[128]) return;
  const int cat   = wsi[132 + g * 4 + 0];
  const int start = wsi[132 + g * 4 + 1];
  const int cnt   = wsi[132 + g * 4 + 2];
  const int n0    = t * BN;

  __shared__ unsigned short As[2][BM * LDA];   // 2 x 10240 B
  __shared__ unsigned short Bs[2][4 * BN * 8]; // 2 x 4096 B

  const int tid  = threadIdx.x;
  const int lane = tid & 63;
  const int w    = tid >> 6;

  // A staging: thread -> (row = tid>>1, khalf = (tid&1)*16), 16 bf16 = uint4 x1... 2 loads of 8
  const int arow  = tid >> 1;
  const int khalf = (tid & 1) * 16;
  const int lb    = arow >> 5;
  const int tok   = arow & 31;
  const int lbc   = lb < (cnt - 1) ? lb : (cnt - 1);
  const int batch = wsi[start + lbc];
  const long grow = (long)(batch * TT + tok);
  const unsigned short* Arow = A + grow * (long)K + khalf;

  // B staging: thread -> kc = w (k rows w*8..w*8+7), col = lane
  const float* Wcol = W + (size_t)cat * (size_t)K * 1024 + n0 + lane;

  f32x4 acc[4][2];
#pragma unroll
  for (int i = 0; i < 4; i++)
#pragma unroll
    for (int j = 0; j < 2; j++) acc[i][j] = (f32x4){0.f, 0.f, 0.f, 0.f};

  const int wm  = (w >> 1) * 64;
  const int wn  = (w & 1) * 32;
  const int kg  = lane >> 4;
  const int c16 = lane & 15;

  uint4 a0, a1;
  float br[8];
  auto load_tile = [&](int k0) {
    const uint4* ap = (const uint4*)(Arow + k0);
    a0 = ap[0];
    a1 = ap[1];
    const float* bp = Wcol + (size_t)(k0 + w * 8) * 1024;
#pragma unroll
    for (int r = 0; r < 8; r++) br[r] = bp[(size_t)r * 1024];
  };
  auto store_tile = [&](int buf) {
    *(uint4*)&As[buf][arow * LDA + khalf]     = a0;
    *(uint4*)&As[buf][arow * LDA + khalf + 8] = a1;
    uint4 bw = make_uint4(pk2bf(br[0], br[1]), pk2bf(br[2], br[3]),
                          pk2bf(br[4], br[5]), pk2bf(br[6], br[7]));
    *(uint4*)&Bs[buf][(w * BN + lane) * 8] = bw;
  };

  load_tile(0);
  store_tile(0);
  int cur = 0;

  for (int k0 = 0; k0 < K; k0 += BK) {
    __syncthreads();  // buf[cur] written & prior reads of buf[cur^1] done
    const bool more = (k0 + BK) < K;
    if (more) load_tile(k0 + BK);  // issue early; consumed after MFMA

    short8 afrag[4], bfrag[2];
#pragma unroll
    for (int i = 0; i < 4; i++)
      afrag[i] = *(const short8*)&As[cur][(wm + i * 16 + c16) * LDA + kg * 8];
#pragma unroll
    for (int j = 0; j < 2; j++)
      bfrag[j] = *(const short8*)&Bs[cur][(kg * BN + wn + j * 16 + c16) * 8];
#pragma unroll
    for (int i = 0; i < 4; i++)
#pragma unroll
      for (int j = 0; j < 2; j++)
        acc[i][j] = __builtin_amdgcn_mfma_f32_16x16x32_bf16(afrag[i], bfrag[j], acc[i][j], 0, 0, 0);

    if (more) store_tile(cur ^ 1);  // vmcnt wait lands here, after MFMA issue
    cur ^= 1;
  }

  // ---------- epilogue ----------
  const int rquad = (lane >> 4) * 4;
#pragma unroll
  for (int i = 0; i < 4; i++) {
#pragma unroll
    for (int j = 0; j < 2; j++) {
      int gcol = n0 + wn + j * 16 + c16;
      float bb = bias[cat * 1024 + gcol];
#pragma unroll
      for (int r = 0; r < 4; r++) {
        int lrow = wm + i * 16 + rquad + r;
        int lb2 = lrow >> 5;
        if (lb2 < cnt) {
          int b2 = wsi[start + lb2];
          long orow = (long)(b2 * TT + (lrow & 31));
          float v = acc[i][j][r] + bb;
          if constexpr (LAYER == 1) {
            v = fmaxf(v, 0.f);
            ((unsigned short*)Out)[orow * DMID + gcol] =
                __builtin_bit_cast(unsigned short, __float2bfloat16(v));
          } else {
            ((float*)Out)[orow * 1024 + gcol] = v;
          }
        }
      }
    }
  }
}

extern "C" void kernel_launch(void* const* d_in, const int* in_sizes, int n_in,
                              void* d_out, int out_size, void* d_ws, size_t ws_size,
                              hipStream_t stream) {
  const float* x       = (const float*)d_in[0];
  const int*   cat_ids = (const int*)d_in[1];
  const float* W1      = (const float*)d_in[2];
  const float* b1      = (const float*)d_in[3];
  const float* W2      = (const float*)d_in[4];
  const float* b2      = (const float*)d_in[5];
  float* out = (float*)d_out;

  int* wsi = (int*)d_ws;
  unsigned short* xbf    = (unsigned short*)((char*)d_ws + 8192);
  unsigned short* hidden = (unsigned short*)((char*)d_ws + 8192 + 12582912);

  build_groups<<<dim3(1), dim3(128), 0, stream>>>(cat_ids, wsi);
  cvt_x_bf16<<<dim3(3072), dim3(256), 0, stream>>>(x, xbf);
  mlp_gemm<1><<<dim3(NTILE * MAXG), dim3(256), 0, stream>>>(
      xbf, W1, b1, wsi, (void*)hidden, DIN);
  mlp_gemm<2><<<dim3(NTILE * MAXG), dim3(256), 0, stream>>>(
      hidden, W2, b2, wsi, (void*)out, DMID);
}